// Round 1
// baseline (1187.893 us; speedup 1.0000x reference)
//
#include <hip/hip_runtime.h>
#include <stdint.h>

#define NUM_CHARS 128
#define BATCH 8192
#define SEQ 40
#define HIDDEN 256
#define ZDIM 1024   /* 4*HIDDEN */
#define KDIM 384    /* 256 h + 128 one-hot */
#define NKK 24      /* KDIM/16 */
#define STRIDE_H 392 /* padded bf16 row stride: 384 used, 196 dwords ≡ 4 mod 32 (same class as prior 264) */

typedef __bf16 bf16x8 __attribute__((ext_vector_type(8)));
typedef float floatx16 __attribute__((ext_vector_type(16)));

__device__ __forceinline__ unsigned short f2bf(float f) {
    union { float f; uint32_t u; } v; v.f = f;
    uint32_t u = v.u;
    u += 0x7FFFu + ((u >> 16) & 1u); // RNE
    return (unsigned short)(u >> 16);
}

// ---- prep: W = [Wh; Wx] fragment-contiguous ----
// WhXFrag[ntile(32)][kk(24)][lane(64)][j(8)] bf16 ; element = W[k][n],
// k = kk*16 + (lane>>5)*8 + j  (k<256 -> Wh[k], else Wx[k-256]), n = ntile*32 + (lane&31)
__global__ void prep_whx(const float* __restrict__ Wh, const float* __restrict__ Wx,
                         unsigned short* __restrict__ out) {
    int idx = blockIdx.x * blockDim.x + threadIdx.x; // 0..393215
    int j = idx & 7;
    int lane = (idx >> 3) & 63;
    int q = idx >> 9;        // ntile*24 + kk
    int kk = q % 24;
    int ntile = q / 24;
    int k = kk * 16 + ((lane >> 5) << 3) + j;
    int n = (ntile << 5) + (lane & 31);
    float v = (k < 256) ? Wh[k * ZDIM + n] : Wx[(k - 256) * ZDIM + n];
    out[idx] = f2bf(v);
}

// WdFrag[ntile(4)][kk(16)][lane(64)][j(8)] bf16 ; element = Wd[k][n]
__global__ void prep_wd(const float* __restrict__ Wd, unsigned short* __restrict__ out) {
    int idx = blockIdx.x * blockDim.x + threadIdx.x; // 0..32767
    int j = idx & 7;
    int lane = (idx >> 3) & 63;
    int kk = (idx >> 9) & 15;
    int nt = idx >> 13;
    int k = kk * 16 + ((lane >> 5) << 3) + j;
    int n = (nt << 5) + (lane & 31);
    out[idx] = f2bf(Wd[k * NUM_CHARS + n]);
}

// ---- main: 256 blocks x 512 threads; block owns 32 batch rows, 1 block/CU ----
__global__ __launch_bounds__(512, 2) void lstm_main(
    const int* __restrict__ inputs, const unsigned short* __restrict__ WhXFrag,
    const float* __restrict__ b, const unsigned short* __restrict__ WdFrag,
    const float* __restrict__ bd, float* __restrict__ out)
{
    __shared__ int tok[32 * SEQ];                        //  5.1 KB
    __shared__ unsigned short hbuf[2][32 * STRIDE_H];    // 49.0 KB (h cols 0..255 | one-hot cols 256..383)
    __shared__ float red[2][4][32];                      //  1.0 KB

    const int tid = threadIdx.x;
    const int w = tid >> 6;        // wave 0..7, owns z-cols g*256 + w*32 .. +32 per gate g
    const int lane = tid & 63;
    const int r0 = blockIdx.x * 32;

    // stage tokens + zero both h/one-hot buffers
    for (int i = tid; i < 32 * SEQ; i += 512) tok[i] = inputs[r0 * SEQ + i];
    {
        int* hz = (int*)&hbuf[0][0];
        for (int i = tid; i < 32 * STRIDE_H; i += 512) hz[i] = 0; // 2*32*392 ushorts = 32*392 ints
    }
    __syncthreads();
    // seed one-hot(x_0) into buffer 0
    if (tid < 32) hbuf[0][tid * STRIDE_H + 256 + tok[tid * SEQ]] = 0x3F80;

    // per-gate global base pointers into the fragment table
    const unsigned short* wb[4];
#pragma unroll
    for (int g = 0; g < 4; ++g)
        wb[g] = WhXFrag + ((size_t)((g * 8 + w) * NKK * 64) + lane) * 8;

    // resident B fragments: kk 0..7 (128 VGPRs, reused 40x)
    bf16x8 BfR[4][8];
#pragma unroll
    for (int g = 0; g < 4; ++g)
#pragma unroll
        for (int kk = 0; kk < 8; ++kk)
            BfR[g][kk] = *(const bf16x8*)(wb[g] + (kk << 9));

    const int hcol = (w << 5) + (lane & 31);
    float bval[4];
#pragma unroll
    for (int g = 0; g < 4; ++g) bval[g] = b[g * 256 + hcol];

    floatx16 c_st;
#pragma unroll
    for (int i = 0; i < 16; ++i) c_st[i] = 0.f;

    // C/D layout: col = lane&31, row = (i&3) + 8*(i>>2) + rbase
    const int rbase = 4 * (lane >> 5);
    const int abase = (lane & 31) * STRIDE_H + ((lane >> 5) << 3);
    const float L2E = 1.4426950408889634f;
    int cur = 0;
    __syncthreads();

#pragma unroll 1
    for (int t = 0; t < SEQ; ++t) {
        const unsigned short* hb = &hbuf[cur][0];
        unsigned short* hn = &hbuf[cur ^ 1][0];

        floatx16 acc[4];
#pragma unroll
        for (int g = 0; g < 4; ++g)
#pragma unroll
            for (int i = 0; i < 16; ++i) acc[g][i] = bval[g];

        // kk 0..7: resident fragments
#pragma unroll
        for (int kk = 0; kk < 8; ++kk) {
            bf16x8 af = *(const bf16x8*)(hb + abase + kk * 16);
            acc[0] = __builtin_amdgcn_mfma_f32_32x32x16_bf16(af, BfR[0][kk], acc[0], 0, 0, 0);
            acc[1] = __builtin_amdgcn_mfma_f32_32x32x16_bf16(af, BfR[1][kk], acc[1], 0, 0, 0);
            acc[2] = __builtin_amdgcn_mfma_f32_32x32x16_bf16(af, BfR[2][kk], acc[2], 0, 0, 0);
            acc[3] = __builtin_amdgcn_mfma_f32_32x32x16_bf16(af, BfR[3][kk], acc[3], 0, 0, 0);
        }
        // kk 8..23: streamed, coalesced 16B/lane from L2-resident table
#pragma unroll
        for (int kk = 8; kk < NKK; ++kk) {
            bf16x8 b0 = *(const bf16x8*)(wb[0] + (kk << 9));
            bf16x8 b1 = *(const bf16x8*)(wb[1] + (kk << 9));
            bf16x8 b2 = *(const bf16x8*)(wb[2] + (kk << 9));
            bf16x8 b3 = *(const bf16x8*)(wb[3] + (kk << 9));
            bf16x8 af = *(const bf16x8*)(hb + abase + kk * 16);
            acc[0] = __builtin_amdgcn_mfma_f32_32x32x16_bf16(af, b0, acc[0], 0, 0, 0);
            acc[1] = __builtin_amdgcn_mfma_f32_32x32x16_bf16(af, b1, acc[1], 0, 0, 0);
            acc[2] = __builtin_amdgcn_mfma_f32_32x32x16_bf16(af, b2, acc[2], 0, 0, 0);
            acc[3] = __builtin_amdgcn_mfma_f32_32x32x16_bf16(af, b3, acc[3], 0, 0, 0);
        }

        // gates (keras i,f,g,o), c fp32 in regs, h -> bf16 LDS (other buffer)
#pragma unroll
        for (int i = 0; i < 16; ++i) {
            float zi = acc[0][i], zf = acc[1][i], zg = acc[2][i], zo = acc[3][i];
            float si = __builtin_amdgcn_rcpf(1.f + __builtin_amdgcn_exp2f(-zi * L2E));
            float sf = __builtin_amdgcn_rcpf(1.f + __builtin_amdgcn_exp2f(-zf * L2E));
            float so = __builtin_amdgcn_rcpf(1.f + __builtin_amdgcn_exp2f(-zo * L2E));
            float tg = 1.f - 2.f * __builtin_amdgcn_rcpf(1.f + __builtin_amdgcn_exp2f(2.f * L2E * zg));
            float c = sf * c_st[i] + si * tg;
            c_st[i] = c;
            float tc = 1.f - 2.f * __builtin_amdgcn_rcpf(1.f + __builtin_amdgcn_exp2f(2.f * L2E * c));
            int r = (i & 3) + 8 * (i >> 2) + rbase;
            hn[r * STRIDE_H + hcol] = f2bf(so * tc);
        }

        // one-hot maintenance in buffer cur^1 (readers of its x-section finished at the t-1 barrier):
        // clear bit of x_{t-1}, set bit of x_{t+1}. Order matters when tokens equal.
        if (tid < 32) {
            unsigned short* xs = hn + tid * STRIDE_H + 256;
            if (t >= 1) xs[tok[tid * SEQ + t - 1]] = 0;
            if (t + 1 < SEQ) xs[tok[tid * SEQ + t + 1]] = 0x3F80;
        }
        __syncthreads();
        cur ^= 1;
    }

    // ---- logits = h @ Wd + bd, softmax from registers (waves 0..3, vocab ntile = w) ----
    floatx16 accd;
    float p[16];
    float mx[16];
    const unsigned short* hb = &hbuf[cur][0];
    if (w < 4) {
        float bdv = bd[(w << 5) + (lane & 31)];
#pragma unroll
        for (int i = 0; i < 16; ++i) accd[i] = bdv;
#pragma unroll
        for (int kk = 0; kk < 16; ++kk) {
            bf16x8 af = *(const bf16x8*)(hb + abase + kk * 16);
            bf16x8 bfd = *(const bf16x8*)(WdFrag + (((w * 16 + kk) << 6) + lane) * 8);
            accd = __builtin_amdgcn_mfma_f32_32x32x16_bf16(af, bfd, accd, 0, 0, 0);
        }
        // per-row max over this wave's 32 cols (32-lane half holds one row per reg)
#pragma unroll
        for (int i = 0; i < 16; ++i) {
            float m = accd[i];
#pragma unroll
            for (int off = 1; off < 32; off <<= 1) m = fmaxf(m, __shfl_xor(m, off, 32));
            mx[i] = m;
        }
        if ((lane & 31) == 0) {
#pragma unroll
            for (int i = 0; i < 16; ++i) red[0][w][(i & 3) + 8 * (i >> 2) + rbase] = mx[i];
        }
    }
    __syncthreads();
    if (w < 4) {
#pragma unroll
        for (int i = 0; i < 16; ++i) {
            int r = (i & 3) + 8 * (i >> 2) + rbase;
            float M = fmaxf(fmaxf(red[0][0][r], red[0][1][r]),
                            fmaxf(red[0][2][r], red[0][3][r]));
            float e = __builtin_amdgcn_exp2f((accd[i] - M) * L2E);
            p[i] = e;
            float s = e;
#pragma unroll
            for (int off = 1; off < 32; off <<= 1) s += __shfl_xor(s, off, 32);
            mx[i] = s; // partial row sum for this wave's 32 cols
        }
        if ((lane & 31) == 0) {
#pragma unroll
            for (int i = 0; i < 16; ++i) red[1][w][(i & 3) + 8 * (i >> 2) + rbase] = mx[i];
        }
    }
    __syncthreads();
    if (w < 4) {
#pragma unroll
        for (int i = 0; i < 16; ++i) {
            int r = (i & 3) + 8 * (i >> 2) + rbase;
            float tot = red[1][0][r] + red[1][1][r] + red[1][2][r] + red[1][3][r];
            out[(size_t)(r0 + r) * NUM_CHARS + (w << 5) + (lane & 31)] =
                p[i] * __builtin_amdgcn_rcpf(tot);
        }
    }
}

extern "C" void kernel_launch(void* const* d_in, const int* in_sizes, int n_in,
                              void* d_out, int out_size, void* d_ws, size_t ws_size,
                              hipStream_t stream) {
    const int*   inputs = (const int*)d_in[0];
    const float* Wx = (const float*)d_in[1];
    const float* Wh = (const float*)d_in[2];
    const float* b  = (const float*)d_in[3];
    const float* Wd = (const float*)d_in[4];
    const float* bd = (const float*)d_in[5];
    float* out = (float*)d_out;

    unsigned short* WhXFrag = (unsigned short*)d_ws;                         // 768 KB
    unsigned short* WdFrag  = (unsigned short*)((char*)d_ws + (768 << 10));  //  64 KB

    prep_whx<<<393216 / 256, 256, 0, stream>>>(Wh, Wx, WhXFrag);
    prep_wd <<< 32768 / 256, 256, 0, stream>>>(Wd, WdFrag);
    lstm_main<<<256, 512, 0, stream>>>(inputs, WhXFrag, b, WdFrag, bd, out);
}

// Round 2
// 483.334 us; speedup vs baseline: 2.4577x; 2.4577x over previous
//
#include <hip/hip_runtime.h>
#include <stdint.h>

#define NUM_CHARS 128
#define BATCH 8192
#define SEQ 40
#define HIDDEN 256
#define ZDIM 1024   /* 4*HIDDEN */
#define SH 264      /* padded h row stride in ushorts: 132 dwords == 4 mod 32 -> conflict-free b128 */
#define LKK 4       /* kk 0..3 staged in LDS (128 KB) */
#define RKK 2       /* kk 4..5 register-resident (32 VGPRs) */

typedef __bf16 bf16x8 __attribute__((ext_vector_type(8)));
typedef float floatx16 __attribute__((ext_vector_type(16)));

__device__ __forceinline__ unsigned short f2bf(float f) {
    union { float f; uint32_t u; } v; v.f = f;
    uint32_t u = v.u;
    u += 0x7FFFu + ((u >> 16) & 1u); // RNE
    return (unsigned short)(u >> 16);
}

// WhFrag[ntile(32)][kk(16)][lane(64)][j(8)] bf16 ; element = Wh[k][n],
// k = kk*16 + (lane>>5)*8 + j, n = ntile*32 + (lane&31)
__global__ void prep_wh(const float* __restrict__ Wh, unsigned short* __restrict__ out) {
    int idx = blockIdx.x * blockDim.x + threadIdx.x; // 0..262143
    int j = idx & 7;
    int lane = (idx >> 3) & 63;
    int kk = (idx >> 9) & 15;
    int ntile = idx >> 13;
    int k = kk * 16 + ((lane >> 5) << 3) + j;
    int n = (ntile << 5) + (lane & 31);
    out[idx] = f2bf(Wh[k * ZDIM + n]);
}

// WxbB[vocab(128)][1024] bf16 = Wx + b (bias folded)
__global__ void prep_wxb16(const float* __restrict__ Wx, const float* __restrict__ b,
                           unsigned short* __restrict__ out) {
    int idx = blockIdx.x * blockDim.x + threadIdx.x; // 0..131071
    out[idx] = f2bf(Wx[idx] + b[idx & (ZDIM - 1)]);
}

// WdFrag[ntile(4)][kk(16)][lane(64)][j(8)] bf16 ; element = Wd[k][n]
__global__ void prep_wd(const float* __restrict__ Wd, unsigned short* __restrict__ out) {
    int idx = blockIdx.x * blockDim.x + threadIdx.x; // 0..32767
    int j = idx & 7;
    int lane = (idx >> 3) & 63;
    int kk = (idx >> 9) & 15;
    int nt = idx >> 13;
    int k = kk * 16 + ((lane >> 5) << 3) + j;
    int n = (nt << 5) + (lane & 31);
    out[idx] = f2bf(Wd[k * NUM_CHARS + n]);
}

__device__ __forceinline__ void gates_store(floatx16 (&acc)[4], floatx16& c_st,
                                            unsigned short* hb, int rbase, int hcol) {
    const float L2E = 1.4426950408889634f;
#pragma unroll
    for (int i = 0; i < 16; ++i) {
        float zi = acc[0][i], zf = acc[1][i], zg = acc[2][i], zo = acc[3][i];
        float si = __builtin_amdgcn_rcpf(1.f + __builtin_amdgcn_exp2f(-zi * L2E));
        float sf = __builtin_amdgcn_rcpf(1.f + __builtin_amdgcn_exp2f(-zf * L2E));
        float so = __builtin_amdgcn_rcpf(1.f + __builtin_amdgcn_exp2f(-zo * L2E));
        float tg = 1.f - 2.f * __builtin_amdgcn_rcpf(1.f + __builtin_amdgcn_exp2f(2.f * L2E * zg));
        float c = sf * c_st[i] + si * tg;
        c_st[i] = c;
        float tc = 1.f - 2.f * __builtin_amdgcn_rcpf(1.f + __builtin_amdgcn_exp2f(2.f * L2E * c));
        hb[((i & 3) + 8 * (i >> 2) + rbase) * SH + hcol] = f2bf(so * tc);
    }
}

#define MFMA4(AF, B0, B1, B2, B3)                                                   \
    acc[0] = __builtin_amdgcn_mfma_f32_32x32x16_bf16(AF, B0, acc[0], 0, 0, 0);      \
    acc[1] = __builtin_amdgcn_mfma_f32_32x32x16_bf16(AF, B1, acc[1], 0, 0, 0);      \
    acc[2] = __builtin_amdgcn_mfma_f32_32x32x16_bf16(AF, B2, acc[2], 0, 0, 0);      \
    acc[3] = __builtin_amdgcn_mfma_f32_32x32x16_bf16(AF, B3, acc[3], 0, 0, 0);

// ---- main: 256 blocks x 512 threads; block owns 32 batch rows, 1 block/CU ----
__global__ __launch_bounds__(512, 2) void lstm_main(
    const int* __restrict__ inputs, const unsigned short* __restrict__ WhFrag,
    const unsigned short* __restrict__ WxbB, const unsigned short* __restrict__ WdFrag,
    const float* __restrict__ bd, float* __restrict__ out)
{
    __shared__ unsigned short wlds[32 * LKK * 512];   // 128 KB: kk 0..3, all 32 ntiles
    __shared__ unsigned short hbuf[32 * SH];          // 16.5 KB single h buffer
    __shared__ int tok[32 * SEQ];                     //  5.0 KB
    __shared__ float red[2][4][32];                   //  1.0 KB

    const int tid = threadIdx.x;
    const int w = tid >> 6;        // wave 0..7; gate g's n-tile = g*8 + w
    const int lane = tid & 63;
    const int r0 = blockIdx.x * 32;

    // stage tokens (coalesced)
    for (int i = tid; i < 32 * SEQ; i += 512) tok[i] = inputs[r0 * SEQ + i];
    // stage Wh kk 0..3 into LDS: 128 frags x 1KB; frag f = ntile*4 + kk
    for (int c = tid; c < 8192; c += 512) {
        int f = c >> 6, o = c & 63;
        *(bf16x8*)&wlds[(f << 9) + (o << 3)] =
            *(const bf16x8*)&WhFrag[((((f >> 2) << 4) + (f & 3)) << 9) + (o << 3)];
    }

    // streamed-fragment base pointers (per gate), lane offset folded in
    const unsigned short* wsb[4];
#pragma unroll
    for (int g = 0; g < 4; ++g)
        wsb[g] = WhFrag + (((g * 8 + w) * 16) << 9) + (lane << 3);

    // register-resident kk 4..5
    bf16x8 wr[4][RKK];
#pragma unroll
    for (int g = 0; g < 4; ++g)
#pragma unroll
        for (int rk = 0; rk < RKK; ++rk)
            wr[g][rk] = *(const bf16x8*)(wsb[g] + ((LKK + rk) << 9));

    const int hcol = (w << 5) + (lane & 31);
    const int rbase = 4 * (lane >> 5);
    const int abase = (lane & 31) * SH + ((lane >> 5) << 3);

    floatx16 c_st;
#pragma unroll
    for (int i = 0; i < 16; ++i) c_st[i] = 0.f;

    __syncthreads();  // tok + wlds ready

    // ---- t = 0: h0 = 0, so z = Wx[token]+b only ----
    {
        int toff[16];
#pragma unroll
        for (int i = 0; i < 16; ++i)
            toff[i] = tok[((i & 3) + 8 * (i >> 2) + rbase) * SEQ] << 10;
        floatx16 acc[4];
#pragma unroll
        for (int g = 0; g < 4; ++g) {
#pragma unroll
            for (int i = 0; i < 16; ++i) {
                union { uint32_t u; float f; } v;
                v.u = ((uint32_t)WxbB[toff[i] + (g << 8) + hcol]) << 16;
                acc[g][i] = v.f;
            }
        }
        gates_store(acc, c_st, hbuf, rbase, hcol);
    }
    __syncthreads();

    // ---- t = 1..39 ----
#pragma unroll 1
    for (int t = 1; t < SEQ; ++t) {
        // 2-deep streamed double-buffer: preload kk 6,7
        bf16x8 sA[4], sB[4];
#pragma unroll
        for (int g = 0; g < 4; ++g) sA[g] = *(const bf16x8*)(wsb[g] + (6 << 9));
#pragma unroll
        for (int g = 0; g < 4; ++g) sB[g] = *(const bf16x8*)(wsb[g] + (7 << 9));

        // gather z_x = WxB[token] (bf16 -> f32 init of acc)
        int toff[16];
#pragma unroll
        for (int i = 0; i < 16; ++i)
            toff[i] = tok[((i & 3) + 8 * (i >> 2) + rbase) * SEQ + t] << 10;
        floatx16 acc[4];
#pragma unroll
        for (int g = 0; g < 4; ++g) {
#pragma unroll
            for (int i = 0; i < 16; ++i) {
                union { uint32_t u; float f; } v;
                v.u = ((uint32_t)WxbB[toff[i] + (g << 8) + hcol]) << 16;
                acc[g][i] = v.f;
            }
        }

        // kk 0..3: B from LDS
#pragma unroll
        for (int kk = 0; kk < LKK; ++kk) {
            bf16x8 af = *(const bf16x8*)&hbuf[abase + kk * 16];
            bf16x8 b0 = *(const bf16x8*)&wlds[(((0 << 5) + (w << 2) + kk) << 9) + (lane << 3)];
            bf16x8 b1 = *(const bf16x8*)&wlds[(((1 << 5) + (w << 2) + kk) << 9) + (lane << 3)];
            bf16x8 b2 = *(const bf16x8*)&wlds[(((2 << 5) + (w << 2) + kk) << 9) + (lane << 3)];
            bf16x8 b3 = *(const bf16x8*)&wlds[(((3 << 5) + (w << 2) + kk) << 9) + (lane << 3)];
            MFMA4(af, b0, b1, b2, b3)
        }
        // kk 4..5: B register-resident
#pragma unroll
        for (int rk = 0; rk < RKK; ++rk) {
            bf16x8 af = *(const bf16x8*)&hbuf[abase + (LKK + rk) * 16];
            MFMA4(af, wr[0][rk], wr[1][rk], wr[2][rk], wr[3][rk])
        }
        // kk 6..15: streamed from L2, 2-deep pipeline
#pragma unroll
        for (int kk = 6; kk < 16; ++kk) {
            bf16x8 af = *(const bf16x8*)&hbuf[abase + kk * 16];
            if ((kk & 1) == 0) {
                MFMA4(af, sA[0], sA[1], sA[2], sA[3])
                if (kk + 2 < 16) {
#pragma unroll
                    for (int g = 0; g < 4; ++g)
                        sA[g] = *(const bf16x8*)(wsb[g] + ((kk + 2) << 9));
                }
            } else {
                MFMA4(af, sB[0], sB[1], sB[2], sB[3])
                if (kk + 2 < 16) {
#pragma unroll
                    for (int g = 0; g < 4; ++g)
                        sB[g] = *(const bf16x8*)(wsb[g] + ((kk + 2) << 9));
                }
            }
        }

        __syncthreads();                      // all h reads done
        gates_store(acc, c_st, hbuf, rbase, hcol);
        __syncthreads();                      // h_t visible
    }

    // ---- logits = h @ Wd + bd, register softmax (waves 0..3, vocab ntile = w) ----
    floatx16 accd;
    float p[16];
    float mx[16];
    if (w < 4) {
        float bdv = bd[(w << 5) + (lane & 31)];
#pragma unroll
        for (int i = 0; i < 16; ++i) accd[i] = bdv;
#pragma unroll
        for (int kk = 0; kk < 16; ++kk) {
            bf16x8 af = *(const bf16x8*)&hbuf[abase + kk * 16];
            bf16x8 bfd = *(const bf16x8*)(WdFrag + ((((w << 4) + kk) << 6) + lane) * 8);
            accd = __builtin_amdgcn_mfma_f32_32x32x16_bf16(af, bfd, accd, 0, 0, 0);
        }
#pragma unroll
        for (int i = 0; i < 16; ++i) {
            float m = accd[i];
#pragma unroll
            for (int off = 1; off < 32; off <<= 1) m = fmaxf(m, __shfl_xor(m, off, 32));
            mx[i] = m;
        }
        if ((lane & 31) == 0) {
#pragma unroll
            for (int i = 0; i < 16; ++i) red[0][w][(i & 3) + 8 * (i >> 2) + rbase] = mx[i];
        }
    }
    __syncthreads();
    const float L2E = 1.4426950408889634f;
    if (w < 4) {
#pragma unroll
        for (int i = 0; i < 16; ++i) {
            int r = (i & 3) + 8 * (i >> 2) + rbase;
            float M = fmaxf(fmaxf(red[0][0][r], red[0][1][r]),
                            fmaxf(red[0][2][r], red[0][3][r]));
            float e = __builtin_amdgcn_exp2f((accd[i] - M) * L2E);
            p[i] = e;
            float s = e;
#pragma unroll
            for (int off = 1; off < 32; off <<= 1) s += __shfl_xor(s, off, 32);
            mx[i] = s;
        }
        if ((lane & 31) == 0) {
#pragma unroll
            for (int i = 0; i < 16; ++i) red[1][w][(i & 3) + 8 * (i >> 2) + rbase] = mx[i];
        }
    }
    __syncthreads();
    if (w < 4) {
#pragma unroll
        for (int i = 0; i < 16; ++i) {
            int r = (i & 3) + 8 * (i >> 2) + rbase;
            float tot = red[1][0][r] + red[1][1][r] + red[1][2][r] + red[1][3][r];
            out[(size_t)(r0 + r) * NUM_CHARS + (w << 5) + (lane & 31)] =
                p[i] * __builtin_amdgcn_rcpf(tot);
        }
    }
}

extern "C" void kernel_launch(void* const* d_in, const int* in_sizes, int n_in,
                              void* d_out, int out_size, void* d_ws, size_t ws_size,
                              hipStream_t stream) {
    const int*   inputs = (const int*)d_in[0];
    const float* Wx = (const float*)d_in[1];
    const float* Wh = (const float*)d_in[2];
    const float* b  = (const float*)d_in[3];
    const float* Wd = (const float*)d_in[4];
    const float* bd = (const float*)d_in[5];
    float* out = (float*)d_out;

    unsigned short* WhFrag = (unsigned short*)d_ws;                          // 512 KB
    unsigned short* WxbB   = (unsigned short*)((char*)d_ws + (512 << 10));   // 256 KB
    unsigned short* WdFrag = (unsigned short*)((char*)d_ws + (768 << 10));   //  64 KB

    prep_wh   <<<262144 / 256, 256, 0, stream>>>(Wh, WhFrag);
    prep_wxb16<<<131072 / 256, 256, 0, stream>>>(Wx, b, WxbB);
    prep_wd   <<< 32768 / 256, 256, 0, stream>>>(Wd, WdFrag);
    lstm_main<<<256, 512, 0, stream>>>(inputs, WhFrag, WxbB, WdFrag, bd, out);
}